// Round 17
// baseline (143.437 us; speedup 1.0000x reference)
//
#include <hip/hip_runtime.h>
#include <math.h>

#define NT 1024
#define KSEL 100
#define NW0 8      // pass-0 per-wave-pair histogram copies
#define HPAD 260   // per-wave hist stride (words)
#define CCAP 2048  // compact candidate list capacity

// ws layout (floats): ct[3][32][256] | W0T[256][256] | W1T[256][256] | W2T[256][128]
#define OFF_CT   0
#define OFF_W0T  24576
#define OFF_W1T  90112
#define OFF_W2T  155648
#define WS_FLOATS 188416   // 753.6 KB

// ---------- order-preserving float <-> uint key ----------
__device__ __forceinline__ unsigned fkey(float f) {
  unsigned u = __float_as_uint(f);
  return (u & 0x80000000u) ? ~u : (u | 0x80000000u);
}
__device__ __forceinline__ float unfkey(unsigned k) {
  return __uint_as_float((k & 0x80000000u) ? (k & 0x7FFFFFFFu) : ~k);
}
__device__ __forceinline__ unsigned long long lower_mask(int lane) {
  return lane ? (~0ull >> (64 - lane)) : 0ull;
}

// fast tanh: ~10 VALU ops vs ~35 for ocml tanhf. |err| ~1e-7 rel; clamped for big |x|.
__device__ __forceinline__ float fast_tanhf(float x) {
  float ax = fabsf(x);
  float e = __expf(-2.f * ax);
  float r = (1.f - e) * __builtin_amdgcn_rcpf(1.f + e);
  r = (ax > 10.f) ? 1.f : r;
  return copysignf(r, x);
}

// one radix step: suffix-scan over 256 bins (4/lane), wave-uniform krem/prefix update.
__device__ __forceinline__ void scan_step(const unsigned* hb, int ncopies, int lane,
                                          int& krem, unsigned& prefix) {
  const int l4 = lane << 2;
  unsigned h0 = 0, h1 = 0, h2 = 0, h3 = 0;
  #pragma unroll 2
  for (int k = 0; k < ncopies; ++k) {
    const uint4 v = *(const uint4*)&hb[k * HPAD + l4];
    h0 += v.x; h1 += v.y; h2 += v.z; h3 += v.w;
  }
  unsigned csum = h0 + h1 + h2 + h3;
  unsigned S = csum;                         // inclusive suffix over lane chunk sums
  #pragma unroll
  for (int off = 1; off < 64; off <<= 1) {
    unsigned v = __shfl_down(S, off, 64);
    if (lane + off < 64) S += v;
  }
  unsigned tail = S - csum;
  unsigned s3 = tail + h3;
  unsigned s2 = s3 + h2;
  unsigned s1 = s2 + h1;
  unsigned s0v = s1 + h0;
  int ld = -1; unsigned sfx = 0, hd = 0;
  if      ((int)s3  >= krem) { ld = l4 + 3; sfx = s3;  hd = h3; }
  else if ((int)s2  >= krem) { ld = l4 + 2; sfx = s2;  hd = h2; }
  else if ((int)s1  >= krem) { ld = l4 + 1; sfx = s1;  hd = h1; }
  else if ((int)s0v >= krem) { ld = l4 + 0; sfx = s0v; hd = h0; }
  int gd = ld;
  #pragma unroll
  for (int off = 32; off >= 1; off >>= 1) {
    int v = __shfl_down(gd, off, 64);
    if (lane + off < 64) gd = (v > gd) ? v : gd;
  }
  gd = __shfl(gd, 0, 64);
  unsigned osfx = __shfl(sfx, gd >> 2, 64);
  unsigned ohd  = __shfl(hd,  gd >> 2, 64);
  krem -= (int)(osfx - ohd);
  prefix = (prefix << 8) | (unsigned)gd;
}

// ---------- kernel 1: Ct (4-chain ILP) + LDS-tiled transposes ----------
__global__ __launch_bounds__(256) void pqn_precompute(
    const float* __restrict__ W0, const float* __restrict__ W1, const float* __restrict__ W2,
    const float* __restrict__ s0w1, const float* __restrict__ s1w1, const float* __restrict__ s2w1,
    float* __restrict__ ws)
{
  __shared__ float tile[64][65];
  const int bx = blockIdx.x, t = threadIdx.x;
  if (bx < 96) {                              // ---- Ct (h-major) ----
    int id = bx * 256 + t;
    int l = id >> 13, r = id & 8191;
    int h = r >> 8, i = r & 255;              // h block-uniform -> w1 scalar loads
    const float* W  = (l == 0) ? W0 : (l == 1) ? W1 : W2;
    const float* w1 = (l == 0) ? s0w1 : (l == 1) ? s1w1 : s2w1;
    float a0 = 0.f, a1 = 0.f, a2 = 0.f, a3 = 0.f;   // 4 independent chains
    if (l == 2) {
      #pragma unroll 8
      for (int j = 0; j < 128; j += 4) {
        a0 = fmaf(w1[h * 128 + j    ], W[(j    ) * 256 + i], a0);
        a1 = fmaf(w1[h * 128 + j + 1], W[(j + 1) * 256 + i], a1);
        a2 = fmaf(w1[h * 128 + j + 2], W[(j + 2) * 256 + i], a2);
        a3 = fmaf(w1[h * 128 + j + 3], W[(j + 3) * 256 + i], a3);
      }
    } else {
      #pragma unroll 8
      for (int j = 0; j < 256; j += 4) {
        a0 = fmaf(w1[h * 256 + j    ], W[(j    ) * 256 + i], a0);
        a1 = fmaf(w1[h * 256 + j + 1], W[(j + 1) * 256 + i], a1);
        a2 = fmaf(w1[h * 256 + j + 2], W[(j + 2) * 256 + i], a2);
        a3 = fmaf(w1[h * 256 + j + 3], W[(j + 3) * 256 + i], a3);
      }
    }
    ws[OFF_CT + l * 8192 + h * 256 + i] = (a0 + a1) + (a2 + a3);
  } else {                                    // ---- transposes, 64x64 tiles ----
    int tb = bx - 96;
    const float* W; float* WT; int R, tbl;
    if (tb < 16)      { W = W0; WT = ws + OFF_W0T; R = 256; tbl = tb; }
    else if (tb < 32) { W = W1; WT = ws + OFF_W1T; R = 256; tbl = tb - 16; }
    else              { W = W2; WT = ws + OFF_W2T; R = 128; tbl = tb - 32; }
    int tr = tbl >> 2, tc = tbl & 3;
    int c = t & 63, r0 = t >> 6;
    #pragma unroll
    for (int k = 0; k < 16; ++k) {
      int r = r0 + (k << 2);
      tile[r][c] = W[(tr * 64 + r) * 256 + tc * 64 + c];
    }
    __syncthreads();
    int r2 = t & 63;
    #pragma unroll
    for (int k = 0; k < 16; ++k) {
      int c2 = r0 + (k << 2);
      WT[(tc * 64 + c2) * R + tr * 64 + r2] = tile[r2][c2];
    }
  }
}

// fallback-only: recompute C[h][i] directly from global (slow, correct)
__device__ __forceinline__ float slow_c(const float* __restrict__ w1,
                                        const float* __restrict__ W,
                                        int Fout, int h, int i) {
  float c = 0.f;
  for (int j = 0; j < Fout; ++j) c = fmaf(w1[h * Fout + j], W[j * 256 + i], c);
  return c;
}

// ---------- kernel 2: one block per batch ----------
__global__ __launch_bounds__(NT) void pqn_main(
    const float* __restrict__ x,
    const float* __restrict__ W0, const float* __restrict__ W1, const float* __restrict__ W2,
    const float* __restrict__ s0w1, const float* __restrict__ s1w1, const float* __restrict__ s2w1,
    const float* __restrict__ s0b1, const float* __restrict__ s1b1, const float* __restrict__ s2b1,
    const float* __restrict__ s0w2, const float* __restrict__ s1w2, const float* __restrict__ s2w2,
    const float* __restrict__ s0b2, const float* __restrict__ s1b2, const float* __restrict__ s2b2,
    const float* __restrict__ wsr,   // null (fallback) or ws base
    float* __restrict__ out)
{
  __shared__ __align__(16) unsigned keyLds[25 * NT];      // 100 KB: per-thread key cache
  __shared__ __align__(16) unsigned hist0[NW0 * HPAD];    // pass-0 wave-pair copies
  __shared__ __align__(16) unsigned histP[6 * HPAD];      // pass 1 (+ rare-path 2,3)
  __shared__ unsigned candK[CCAP]; __shared__ int candE[CCAP];
  __shared__ __align__(16) float As[2][256];               // layers 1,2 only
  __shared__ __align__(16) float Bs[2][256];
  __shared__ int   path_col[KSEL]; __shared__ float path_t[KSEL];
  __shared__ int   sel_col[KSEL];  __shared__ float sel_s[KSEL]; __shared__ float sel_sc[KSEL];
  __shared__ unsigned tieq[128];
  __shared__ int nsel_s, ntie_s, ncand_s;
  __shared__ int bz_sh[3];
  __shared__ float wts[KSEL];
  __shared__ float partial[8][128];

  const int b = blockIdx.x;
  const int t = threadIdx.x;
  const int lane = t & 63;
  const int w = t >> 6;
  const bool useWs = (wsr != nullptr);
  const float* Ctg = useWs ? (wsr + OFF_CT) : nullptr;
  const float* W0T = useWs ? (wsr + OFF_W0T) : nullptr;
  const float* W1T = useWs ? (wsr + OFF_W1T) : nullptr;
  const float* W2T = useWs ? (wsr + OFF_W2T) : nullptr;

  // ================= entry (overlapped) =================
  if (t >= 256) {                              // A/B for layers 1,2 (512 worker threads)
    int l = 1 + ((t - 256) >> 8), i = t & 255; // l wave-uniform
    if (l <= 2) {
      const float* w2 = (l == 1) ? s1w2 : s2w2;
      float a = 0.f, bn = 0.f;
      if (useWs) {
        const float* ct = Ctg + l * 8192;
        #pragma unroll
        for (int h = 0; h < 32; ++h) {
          float c = ct[h * 256 + i];           // coalesced, 32 independent loads
          float wc = w2[h] * c;
          if (c > 0.f) a += wc; else if (c < 0.f) bn += wc;
        }
      } else {
        const float* W  = (l == 1) ? W1 : W2;
        const float* w1 = (l == 1) ? s1w1 : s2w1;
        const int Fout = (l == 2) ? 128 : 256;
        for (int h = 0; h < 32; ++h) {
          float c = slow_c(w1, W, Fout, h, i);
          float wc = w2[h] * c;
          if (c > 0.f) a += wc; else if (c < 0.f) bn += wc;
        }
      }
      As[l - 1][i] = a; Bs[l - 1][i] = bn;
    }
  } else if (w == 0) {                         // wave 0: bz flags + full layer-0 select
    {
      float v0 = (lane < 32) ? s0b1[lane] : 0.f;
      float v1 = (lane < 32) ? s1b1[lane] : 0.f;
      float v2 = (lane < 32) ? s2b1[lane] : 0.f;
      bz_sh[0] = (__ballot(v0 != 0.f) == 0ull);
      bz_sh[1] = (__ballot(v1 != 0.f) == 0ull);
      bz_sh[2] = (__ballot(v2 != 0.f) == 0ull);
    }
    const float b2v = s0b2[0];
    const float4 xv4 = *(const float4*)(x + b * 256 + lane * 4);
    const float xv[4] = {xv4.x, xv4.y, xv4.z, xv4.w};
    float vq[4] = {b2v, b2v, b2v, b2v};
    if (useWs) {
      #pragma unroll 8
      for (int h = 0; h < 32; ++h) {
        const float4 c4 = *(const float4*)(Ctg + h * 256 + 4 * lane);  // 16B/lane coalesced
        const float w2h = s0w2[h], b1h = s0b1[h];
        vq[0] += w2h * fmaxf(fmaf(xv[0], c4.x, b1h), 0.f);
        vq[1] += w2h * fmaxf(fmaf(xv[1], c4.y, b1h), 0.f);
        vq[2] += w2h * fmaxf(fmaf(xv[2], c4.z, b1h), 0.f);
        vq[3] += w2h * fmaxf(fmaf(xv[3], c4.w, b1h), 0.f);
      }
    } else {
      for (int h = 0; h < 32; ++h) {
        const float w2h = s0w2[h], b1h = s0b1[h];
        #pragma unroll
        for (int q = 0; q < 4; ++q) {
          float c = slow_c(s0w1, W0, 256, h, 4 * lane + q);
          vq[q] += w2h * fmaxf(fmaf(xv[q], c, b1h), 0.f);
        }
      }
    }
    unsigned kq[4];
    #pragma unroll
    for (int q = 0; q < 4; ++q) kq[q] = fkey(vq[q]);

    // in-wave radix select (no barriers); single-copy hist regions (exclusive here)
    int krem = KSEL; unsigned prefix = 0u;
    #pragma unroll
    for (int pass = 0; pass < 4; ++pass) {
      unsigned* hw = (pass == 0) ? hist0 : (histP + (pass - 1) * 2 * HPAD);
      const int l4 = lane << 2;
      hw[l4] = 0u; hw[l4 + 1] = 0u; hw[l4 + 2] = 0u; hw[l4 + 3] = 0u;
      const int shift = 24 - 8 * pass;
      #pragma unroll
      for (int q = 0; q < 4; ++q) {
        bool cand = (pass == 0) || ((kq[q] >> (shift + 8)) == prefix);
        if (cand) atomicAdd(&hw[(kq[q] >> shift) & 255u], 1u);
      }
      scan_step(hw, 1, lane, krem, prefix);
    }
    const unsigned T = prefix;
    int total = 0, ttot = 0;
    #pragma unroll
    for (int q = 0; q < 4; ++q) {
      int e = 4 * lane + q;
      bool sel = kq[q] > T;
      unsigned long long m = __ballot(sel);
      if (sel) {
        int slot = total + (int)__popcll(m & lower_mask(lane));
        path_col[slot] = e; path_t[slot] = xv[q];
      }
      total += (int)__popcll(m);
      bool tie = (kq[q] == T);
      unsigned long long tm = __ballot(tie);
      if (tie) {
        int ts = ttot + (int)__popcll(tm & lower_mask(lane));
        if (ts < 128) tieq[ts] = (unsigned)e;
      }
      ttot += (int)__popcll(tm);
    }
    if (lane == 0) {
      int m = ttot > 128 ? 128 : ttot;
      for (int a2 = 1; a2 < m; ++a2) {
        unsigned v = tieq[a2]; int c = a2 - 1;
        while (c >= 0 && tieq[c] > v) { tieq[c + 1] = tieq[c]; --c; }
        tieq[c + 1] = v;
      }
    }
    const int kt = KSEL - total;
    if (lane < kt) {
      int e = (int)tieq[lane];
      path_col[total + lane] = e; path_t[total + lane] = x[b * 256 + e];
    }
  }
  __syncthreads();   // layer-0 paths + A/B + bz visible

  // ================= layers 1,2 =================
  for (int l = 1; l < 3; ++l) {
    const float* w1 = (l == 1) ? s1w1 : s2w1;
    const float* b1 = (l == 1) ? s1b1 : s2b1;
    const float* w2 = (l == 1) ? s1w2 : s2w2;
    const float  b2v = (l == 1) ? s1b2[0] : s2b2[0];
    const float* Wl = (l == 1) ? W1 : W2;
    const float* Wprev = (l == 1) ? W0 : W1;
    const float* WTprev = (l == 1) ? W0T : W1T;
    const int Fout = (l == 2) ? 128 : 256;
    const bool bz = (bz_sh[l] != 0);
    const float* ctp = useWs ? (Ctg + l * 8192) : nullptr;

    // ---- score phase: 25 elems/thread, e = j*NT + t ; keys -> LDS; inline RLE pass-0 ----
    const int i = t & 255;
    const int pq = t >> 8;
    const float Ai = As[l - 1][i], Bi = Bs[l - 1][i];
    unsigned* histw0 = hist0 + (w >> 1) * HPAD;            // wave-pair copy
    {
      const int l4 = lane << 2;
      histw0[l4] = 0u; histw0[l4 + 1] = 0u; histw0[l4 + 2] = 0u; histw0[l4 + 3] = 0u;
    }
    for (int id = t; id < 2 * HPAD; id += NT) histP[id] = 0u;  // pass-1 hist only
    if (t == 0) { nsel_s = 0; ntie_s = 0; ncand_s = 0; }
    unsigned runD = 0x100u; unsigned runC = 0u;
    if (useWs && bz) {                     // hot path: 8-wide load groups, branch-free inner
      #pragma unroll
      for (int g = 0; g < 25; g += 8) {
        float wv[8], tv[8];
        #pragma unroll
        for (int jj = 0; jj < 8; ++jj) {
          if (g + jj < 25) {
            int p = pq + ((g + jj) << 2);
            tv[jj] = path_t[p];
            wv[jj] = WTprev[(path_col[p] << 8) + i];
          }
        }
        #pragma unroll
        for (int jj = 0; jj < 8; ++jj) {
          if (g + jj < 25) {
            float s = fast_tanhf(wv[jj] * tv[jj]);
            float v = s * (s > 0.f ? Ai : Bi) + b2v;
            unsigned k = fkey(v);
            keyLds[(g + jj) * NT + t] = k;
            unsigned d = k >> 24;
            if (d == runD) ++runC;
            else { if (runC) atomicAdd(&histw0[runD], runC); runD = d; runC = 1u; }
          }
        }
      }
    } else {                               // general path
      #pragma unroll
      for (int g = 0; g < 25; g += 4) {
        float wv[4];
        #pragma unroll
        for (int jj = 0; jj < 4; ++jj) {
          if (g + jj < 25) {
            int p = pq + ((g + jj) << 2);
            wv[jj] = useWs ? WTprev[(path_col[p] << 8) + i]
                           : Wprev[i * 256 + path_col[p]];
          }
        }
        #pragma unroll
        for (int jj = 0; jj < 4; ++jj) {
          if (g + jj < 25) {
            int p = pq + ((g + jj) << 2);
            float s = fast_tanhf(wv[jj] * path_t[p]);
            float v;
            if (bz) v = s * (s > 0.f ? Ai : Bi) + b2v;
            else {
              v = b2v;
              for (int h = 0; h < 32; ++h) {
                float c = useWs ? ctp[h * 256 + i] : slow_c(w1, Wl, Fout, h, i);
                v += w2[h] * fmaxf(fmaf(s, c, b1[h]), 0.f);
              }
            }
            unsigned k = fkey(v);
            keyLds[(g + jj) * NT + t] = k;
            unsigned d = k >> 24;
            if (d == runD) ++runC;
            else { if (runC) atomicAdd(&histw0[runD], runC); runD = d; runC = 1u; }
          }
        }
      }
    }
    if (runC) atomicAdd(&histw0[runD], runC);

    // ---- pass 0 scan ----
    __syncthreads();                                   // b1
    int krem = KSEL; unsigned prefix = 0u;
    scan_step(hist0, NW0, lane, krem, prefix);         // prefix8 (all waves redundantly)

    // ---- pass 1: full read, byte-1 histogram over prefix8 candidates ----
    {
      unsigned* hn = histP + (w & 1) * HPAD;
      #pragma unroll
      for (int j = 0; j < 25; ++j) {
        unsigned k = keyLds[j * NT + t];
        if ((k >> 24) == prefix) atomicAdd(&hn[(k >> 16) & 255u], 1u);
      }
    }
    __syncthreads();                                   // b2
    scan_step(histP, 2, lane, krem, prefix);           // prefix16, krem = slots in tie bin

    // ---- pass 2: full read; early selection (p16>prefix); compact the tie bin ----
    #pragma unroll
    for (int j = 0; j < 25; ++j) {
      unsigned k = keyLds[j * NT + t];
      unsigned p16 = k >> 16;
      if (p16 > prefix) {                              // provably in top-100
        int slot = atomicAdd(&nsel_s, 1);
        int e = j * NT + t; int p = e >> 8;
        float wq = useWs ? WTprev[(path_col[p] << 8) + i] : Wprev[i * 256 + path_col[p]];
        sel_col[slot] = i; sel_s[slot] = fast_tanhf(wq * path_t[p]); sel_sc[slot] = unfkey(k);
      } else if (p16 == prefix) {
        int ci = atomicAdd(&ncand_s, 1);
        if (ci < CCAP) { candK[ci] = k; candE[ci] = j * NT + t; }
      }
    }
    __syncthreads();                                   // b3: candidates complete
    const int ncand = ncand_s;

    if (ncand <= CCAP) {
      // ---- rank-select over compact list: exact stable top-krem (value desc, idx asc) ----
      for (int idx = t; idx < ncand; idx += NT) {
        unsigned k = candK[idx]; int e = candE[idx];
        int rnk = 0;
        for (int j2 = 0; j2 < ncand; ++j2) {
          unsigned kj = candK[j2];
          rnk += (kj > k) || (kj == k && candE[j2] < e);
        }
        if (rnk < krem) {
          int slot = atomicAdd(&nsel_s, 1);
          int ii = e & 255, p = e >> 8;
          float wq = useWs ? WTprev[(path_col[p] << 8) + ii] : Wprev[ii * 256 + path_col[p]];
          sel_col[slot] = ii; sel_s[slot] = fast_tanhf(wq * path_t[p]); sel_sc[slot] = unfkey(k);
        }
      }
    } else {
      // ---- rare fallback: classic passes 2,3 over full keyLds ----
      for (int id = 2 * HPAD + t; id < 6 * HPAD; id += NT) histP[id] = 0u;
      __syncthreads();
      {
        unsigned* hn = histP + 2 * HPAD + (w & 1) * HPAD;
        #pragma unroll
        for (int j = 0; j < 25; ++j) {
          unsigned k = keyLds[j * NT + t];
          if ((k >> 16) == prefix) atomicAdd(&hn[(k >> 8) & 255u], 1u);
        }
      }
      __syncthreads();
      scan_step(histP + 2 * HPAD, 2, lane, krem, prefix); // prefix24
      {
        unsigned* hn = histP + 4 * HPAD + (w & 1) * HPAD;
        #pragma unroll
        for (int j = 0; j < 25; ++j) {
          unsigned k = keyLds[j * NT + t];
          if ((k >> 8) == prefix) atomicAdd(&hn[k & 255u], 1u);
        }
      }
      __syncthreads();
      scan_step(histP + 4 * HPAD, 2, lane, krem, prefix); // T
      const unsigned T = prefix;
      #pragma unroll
      for (int j = 0; j < 25; ++j) {
        unsigned k = keyLds[j * NT + t];
        if ((k >> 16) == (T >> 16)) {
          int e = j * NT + t;
          if (k > T) {
            int slot = atomicAdd(&nsel_s, 1);
            int p = e >> 8;
            float wq = useWs ? WTprev[(path_col[p] << 8) + i] : Wprev[i * 256 + path_col[p]];
            sel_col[slot] = i; sel_s[slot] = fast_tanhf(wq * path_t[p]); sel_sc[slot] = unfkey(k);
          } else if (k == T) {
            int tp = atomicAdd(&ntie_s, 1);
            if (tp < 128) tieq[tp] = (unsigned)e;
          }
        }
      }
    }
    __syncthreads();                                     // b4: selection complete

    if (w == 0) {                                        // wave 0: (rare) ties + path handoff
      const int G = nsel_s;
      const int kt = KSEL - G;                           // 0 on the rank-select path
      if (lane == 0 && kt > 1) {
        int m = ntie_s > 128 ? 128 : ntie_s;
        for (int a2 = 1; a2 < m; ++a2) {
          unsigned v = tieq[a2]; int c = a2 - 1;
          while (c >= 0 && tieq[c] > v) { tieq[c + 1] = tieq[c]; --c; }
          tieq[c + 1] = v;
        }
      }
      if (lane < kt) {
        int e = (int)tieq[lane];
        int ii = e & 255, p = e >> 8;
        float wq = useWs ? WTprev[(path_col[p] << 8) + ii] : Wprev[ii * 256 + path_col[p]];
        sel_col[G + lane] = ii;
        sel_s[G + lane] = fast_tanhf(wq * path_t[p]);
        sel_sc[G + lane] = unfkey(keyLds[0] == 0 ? 0u : 0u) , sel_sc[G + lane] = unfkey(fkey(sel_s[G + lane]));  // unused on rank path
      }
      // NOTE: tie path above only runs in the rare fallback; recompute sel_sc correctly there:
      if (lane < kt) {
        int e = (int)tieq[lane];
        unsigned k = keyLds[(e / NT) * NT + (e % NT)];
        sel_sc[G + lane] = unfkey(k);
      }
      if (l < 2) {
        if (lane < 64) {
          path_col[lane] = sel_col[lane]; path_t[lane] = sel_s[lane];
          if (lane < 36) { path_col[64 + lane] = sel_col[64 + lane]; path_t[64 + lane] = sel_s[64 + lane]; }
        }
      }
    }
    __syncthreads();                                     // paths / sel final
  }

  // ================= epilogue =================
  if (w == 0) {
    float s1v = sel_sc[lane];
    float s2v = (lane < 36) ? sel_sc[64 + lane] : -INFINITY;
    float m = fmaxf(s1v, s2v);
    #pragma unroll
    for (int off = 32; off >= 1; off >>= 1) m = fmaxf(m, __shfl_xor(m, off, 64));
    float e1 = expf(s1v - m);
    float e2 = (lane < 36) ? expf(s2v - m) : 0.f;
    float sv = e1 + e2;
    #pragma unroll
    for (int off = 32; off >= 1; off >>= 1) sv += __shfl_xor(sv, off, 64);
    wts[lane] = e1 * sel_s[lane] / sv;
    if (lane < 36) wts[64 + lane] = e2 * sel_s[64 + lane] / sv;
  }
  __syncthreads();
  {
    const int chunk = w >> 1, half = w & 1;
    const int o = half * 64 + lane;
    const int pb = chunk * 13;
    const int pe = (pb + 13 < KSEL) ? pb + 13 : KSEL;
    float acc = 0.f;
    for (int p = pb; p < pe; ++p) {
      float wq = useWs ? W2T[sel_col[p] * 128 + o] : W2[o * 256 + sel_col[p]];
      acc = fmaf(wq, wts[p], acc);
    }
    partial[chunk][o] = acc;
  }
  __syncthreads();
  if (t < 128) {
    float acc = 0.f;
    #pragma unroll
    for (int c = 0; c < 8; ++c) acc += partial[c][t];
    out[b * 128 + t] = acc;
  }
}

extern "C" void kernel_launch(void* const* d_in, const int* in_sizes, int n_in,
                              void* d_out, int out_size, void* d_ws, size_t ws_size,
                              hipStream_t stream) {
  const float* x    = (const float*)d_in[0];
  const float* W0   = (const float*)d_in[1];
  const float* s0w1 = (const float*)d_in[2];
  const float* s0b1 = (const float*)d_in[3];
  const float* s0w2 = (const float*)d_in[4];
  const float* s0b2 = (const float*)d_in[5];
  const float* W1   = (const float*)d_in[6];
  const float* s1w1 = (const float*)d_in[7];
  const float* s1b1 = (const float*)d_in[8];
  const float* s1w2 = (const float*)d_in[9];
  const float* s1b2 = (const float*)d_in[10];
  const float* W2   = (const float*)d_in[11];
  const float* s2w1 = (const float*)d_in[12];
  const float* s2b1 = (const float*)d_in[13];
  const float* s2w2 = (const float*)d_in[14];
  const float* s2b2 = (const float*)d_in[15];
  float* out = (float*)d_out;
  float* ws  = (float*)d_ws;

  const bool haveWs = ws_size >= (size_t)WS_FLOATS * sizeof(float);
  const float* wsr = nullptr;
  if (haveWs) {
    pqn_precompute<<<136, 256, 0, stream>>>(W0, W1, W2, s0w1, s1w1, s2w1, ws);
    wsr = ws;
  }
  pqn_main<<<16, NT, 0, stream>>>(x, W0, W1, W2,
                                  s0w1, s1w1, s2w1,
                                  s0b1, s1b1, s2b1,
                                  s0w2, s1w2, s2w2,
                                  s0b2, s1b2, s2b2,
                                  wsr, out);
}

// Round 18
// 138.648 us; speedup vs baseline: 1.0345x; 1.0345x over previous
//
#include <hip/hip_runtime.h>
#include <math.h>

#define NT 1024
#define KSEL 100
#define NW0 8      // pass-0 per-wave-pair histogram copies
#define HPAD 260   // per-wave hist stride (words)
#define CCAP 2048  // compact candidate list capacity

// ws layout (floats): ct[3][32][256] | W0T[256][256] | W1T[256][256] | W2T[256][128]
#define OFF_CT   0
#define OFF_W0T  24576
#define OFF_W1T  90112
#define OFF_W2T  155648
#define WS_FLOATS 188416   // 753.6 KB

// ---------- order-preserving float <-> uint key ----------
__device__ __forceinline__ unsigned fkey(float f) {
  unsigned u = __float_as_uint(f);
  return (u & 0x80000000u) ? ~u : (u | 0x80000000u);
}
__device__ __forceinline__ float unfkey(unsigned k) {
  return __uint_as_float((k & 0x80000000u) ? (k & 0x7FFFFFFFu) : ~k);
}
__device__ __forceinline__ unsigned long long lower_mask(int lane) {
  return lane ? (~0ull >> (64 - lane)) : 0ull;
}

// fast tanh: ~10 VALU ops vs ~35 for ocml tanhf. |err| ~1e-7 rel; clamped for big |x|.
__device__ __forceinline__ float fast_tanhf(float x) {
  float ax = fabsf(x);
  float e = __expf(-2.f * ax);
  float r = (1.f - e) * __builtin_amdgcn_rcpf(1.f + e);
  r = (ax > 10.f) ? 1.f : r;
  return copysignf(r, x);
}

// one radix step: suffix-scan over 256 bins (4/lane), wave-uniform krem/prefix update.
__device__ __forceinline__ void scan_step(const unsigned* hb, int ncopies, int lane,
                                          int& krem, unsigned& prefix) {
  const int l4 = lane << 2;
  unsigned h0 = 0, h1 = 0, h2 = 0, h3 = 0;
  #pragma unroll 2
  for (int k = 0; k < ncopies; ++k) {
    const uint4 v = *(const uint4*)&hb[k * HPAD + l4];
    h0 += v.x; h1 += v.y; h2 += v.z; h3 += v.w;
  }
  unsigned csum = h0 + h1 + h2 + h3;
  unsigned S = csum;                         // inclusive suffix over lane chunk sums
  #pragma unroll
  for (int off = 1; off < 64; off <<= 1) {
    unsigned v = __shfl_down(S, off, 64);
    if (lane + off < 64) S += v;
  }
  unsigned tail = S - csum;
  unsigned s3 = tail + h3;
  unsigned s2 = s3 + h2;
  unsigned s1 = s2 + h1;
  unsigned s0v = s1 + h0;
  int ld = -1; unsigned sfx = 0, hd = 0;
  if      ((int)s3  >= krem) { ld = l4 + 3; sfx = s3;  hd = h3; }
  else if ((int)s2  >= krem) { ld = l4 + 2; sfx = s2;  hd = h2; }
  else if ((int)s1  >= krem) { ld = l4 + 1; sfx = s1;  hd = h1; }
  else if ((int)s0v >= krem) { ld = l4 + 0; sfx = s0v; hd = h0; }
  int gd = ld;
  #pragma unroll
  for (int off = 32; off >= 1; off >>= 1) {
    int v = __shfl_down(gd, off, 64);
    if (lane + off < 64) gd = (v > gd) ? v : gd;
  }
  gd = __shfl(gd, 0, 64);
  unsigned osfx = __shfl(sfx, gd >> 2, 64);
  unsigned ohd  = __shfl(hd,  gd >> 2, 64);
  krem -= (int)(osfx - ohd);
  prefix = (prefix << 8) | (unsigned)gd;
}

// ---------- kernel 1: Ct (4-chain ILP) + LDS-tiled transposes ----------
__global__ __launch_bounds__(256) void pqn_precompute(
    const float* __restrict__ W0, const float* __restrict__ W1, const float* __restrict__ W2,
    const float* __restrict__ s0w1, const float* __restrict__ s1w1, const float* __restrict__ s2w1,
    float* __restrict__ ws)
{
  __shared__ float tile[64][65];
  const int bx = blockIdx.x, t = threadIdx.x;
  if (bx < 96) {                              // ---- Ct (h-major) ----
    int id = bx * 256 + t;
    int l = id >> 13, r = id & 8191;
    int h = r >> 8, i = r & 255;              // h block-uniform -> w1 scalar loads
    const float* W  = (l == 0) ? W0 : (l == 1) ? W1 : W2;
    const float* w1 = (l == 0) ? s0w1 : (l == 1) ? s1w1 : s2w1;
    float a0 = 0.f, a1 = 0.f, a2 = 0.f, a3 = 0.f;   // 4 independent chains
    if (l == 2) {
      #pragma unroll 8
      for (int j = 0; j < 128; j += 4) {
        a0 = fmaf(w1[h * 128 + j    ], W[(j    ) * 256 + i], a0);
        a1 = fmaf(w1[h * 128 + j + 1], W[(j + 1) * 256 + i], a1);
        a2 = fmaf(w1[h * 128 + j + 2], W[(j + 2) * 256 + i], a2);
        a3 = fmaf(w1[h * 128 + j + 3], W[(j + 3) * 256 + i], a3);
      }
    } else {
      #pragma unroll 8
      for (int j = 0; j < 256; j += 4) {
        a0 = fmaf(w1[h * 256 + j    ], W[(j    ) * 256 + i], a0);
        a1 = fmaf(w1[h * 256 + j + 1], W[(j + 1) * 256 + i], a1);
        a2 = fmaf(w1[h * 256 + j + 2], W[(j + 2) * 256 + i], a2);
        a3 = fmaf(w1[h * 256 + j + 3], W[(j + 3) * 256 + i], a3);
      }
    }
    ws[OFF_CT + l * 8192 + h * 256 + i] = (a0 + a1) + (a2 + a3);
  } else {                                    // ---- transposes, 64x64 tiles ----
    int tb = bx - 96;
    const float* W; float* WT; int R, tbl;
    if (tb < 16)      { W = W0; WT = ws + OFF_W0T; R = 256; tbl = tb; }
    else if (tb < 32) { W = W1; WT = ws + OFF_W1T; R = 256; tbl = tb - 16; }
    else              { W = W2; WT = ws + OFF_W2T; R = 128; tbl = tb - 32; }
    int tr = tbl >> 2, tc = tbl & 3;
    int c = t & 63, r0 = t >> 6;
    #pragma unroll
    for (int k = 0; k < 16; ++k) {
      int r = r0 + (k << 2);
      tile[r][c] = W[(tr * 64 + r) * 256 + tc * 64 + c];
    }
    __syncthreads();
    int r2 = t & 63;
    #pragma unroll
    for (int k = 0; k < 16; ++k) {
      int c2 = r0 + (k << 2);
      WT[(tc * 64 + c2) * R + tr * 64 + r2] = tile[r2][c2];
    }
  }
}

// fallback-only: recompute C[h][i] directly from global (slow, correct)
__device__ __forceinline__ float slow_c(const float* __restrict__ w1,
                                        const float* __restrict__ W,
                                        int Fout, int h, int i) {
  float c = 0.f;
  for (int j = 0; j < Fout; ++j) c = fmaf(w1[h * Fout + j], W[j * 256 + i], c);
  return c;
}

// ---------- kernel 2: one block per batch ----------
__global__ __launch_bounds__(NT) void pqn_main(
    const float* __restrict__ x,
    const float* __restrict__ W0, const float* __restrict__ W1, const float* __restrict__ W2,
    const float* __restrict__ s0w1, const float* __restrict__ s1w1, const float* __restrict__ s2w1,
    const float* __restrict__ s0b1, const float* __restrict__ s1b1, const float* __restrict__ s2b1,
    const float* __restrict__ s0w2, const float* __restrict__ s1w2, const float* __restrict__ s2w2,
    const float* __restrict__ s0b2, const float* __restrict__ s1b2, const float* __restrict__ s2b2,
    const float* __restrict__ wsr,   // null (fallback) or ws base
    float* __restrict__ out)
{
  __shared__ __align__(16) unsigned keyLds[25 * NT];      // 100 KB: per-thread key cache
  __shared__ __align__(16) unsigned hist0[NW0 * HPAD];    // pass-0 wave-pair copies
  __shared__ __align__(16) unsigned histP[6 * HPAD];      // pass 1 (+ rare-path 2,3)
  __shared__ unsigned candK[CCAP]; __shared__ int candE[CCAP];
  __shared__ __align__(16) float As[2][256];               // layers 1,2 only
  __shared__ __align__(16) float Bs[2][256];
  __shared__ int   path_colb[2][KSEL]; __shared__ float path_tb[2][KSEL];  // double-buffered
  __shared__ int   sel_col[KSEL];  __shared__ float sel_s[KSEL]; __shared__ float sel_sc[KSEL];
  __shared__ unsigned tieq[128];
  __shared__ int nsel_s, ntie_s, ncand_s;
  __shared__ int bz_sh[3];
  __shared__ float wts[KSEL];
  __shared__ float partial[8][128];

  const int b = blockIdx.x;
  const int t = threadIdx.x;
  const int lane = t & 63;
  const int w = t >> 6;
  const bool useWs = (wsr != nullptr);
  const float* Ctg = useWs ? (wsr + OFF_CT) : nullptr;
  const float* W0T = useWs ? (wsr + OFF_W0T) : nullptr;
  const float* W1T = useWs ? (wsr + OFF_W1T) : nullptr;
  const float* W2T = useWs ? (wsr + OFF_W2T) : nullptr;

  // ================= entry (overlapped) =================
  if (t >= 256) {                              // A/B for layers 1,2 (512 worker threads)
    int l = 1 + ((t - 256) >> 8), i = t & 255; // l wave-uniform
    if (l <= 2) {
      const float* w2 = (l == 1) ? s1w2 : s2w2;
      float a = 0.f, bn = 0.f;
      if (useWs) {
        const float* ct = Ctg + l * 8192;
        #pragma unroll
        for (int h = 0; h < 32; ++h) {
          float c = ct[h * 256 + i];           // coalesced, 32 independent loads
          float wc = w2[h] * c;
          if (c > 0.f) a += wc; else if (c < 0.f) bn += wc;
        }
      } else {
        const float* W  = (l == 1) ? W1 : W2;
        const float* w1 = (l == 1) ? s1w1 : s2w1;
        const int Fout = (l == 2) ? 128 : 256;
        for (int h = 0; h < 32; ++h) {
          float c = slow_c(w1, W, Fout, h, i);
          float wc = w2[h] * c;
          if (c > 0.f) a += wc; else if (c < 0.f) bn += wc;
        }
      }
      As[l - 1][i] = a; Bs[l - 1][i] = bn;
    }
  } else if (w == 0) {                         // wave 0: bz flags + full layer-0 select
    {
      float v0 = (lane < 32) ? s0b1[lane] : 0.f;
      float v1 = (lane < 32) ? s1b1[lane] : 0.f;
      float v2 = (lane < 32) ? s2b1[lane] : 0.f;
      bz_sh[0] = (__ballot(v0 != 0.f) == 0ull);
      bz_sh[1] = (__ballot(v1 != 0.f) == 0ull);
      bz_sh[2] = (__ballot(v2 != 0.f) == 0ull);
    }
    const float b2v = s0b2[0];
    const float4 xv4 = *(const float4*)(x + b * 256 + lane * 4);
    const float xv[4] = {xv4.x, xv4.y, xv4.z, xv4.w};
    float vq[4] = {b2v, b2v, b2v, b2v};
    if (useWs) {
      #pragma unroll 8
      for (int h = 0; h < 32; ++h) {
        const float4 c4 = *(const float4*)(Ctg + h * 256 + 4 * lane);  // 16B/lane coalesced
        const float w2h = s0w2[h], b1h = s0b1[h];
        vq[0] += w2h * fmaxf(fmaf(xv[0], c4.x, b1h), 0.f);
        vq[1] += w2h * fmaxf(fmaf(xv[1], c4.y, b1h), 0.f);
        vq[2] += w2h * fmaxf(fmaf(xv[2], c4.z, b1h), 0.f);
        vq[3] += w2h * fmaxf(fmaf(xv[3], c4.w, b1h), 0.f);
      }
    } else {
      for (int h = 0; h < 32; ++h) {
        const float w2h = s0w2[h], b1h = s0b1[h];
        #pragma unroll
        for (int q = 0; q < 4; ++q) {
          float c = slow_c(s0w1, W0, 256, h, 4 * lane + q);
          vq[q] += w2h * fmaxf(fmaf(xv[q], c, b1h), 0.f);
        }
      }
    }
    unsigned kq[4];
    #pragma unroll
    for (int q = 0; q < 4; ++q) kq[q] = fkey(vq[q]);

    // in-wave radix select (no barriers); single-copy hist regions (exclusive here)
    int krem = KSEL; unsigned prefix = 0u;
    #pragma unroll
    for (int pass = 0; pass < 4; ++pass) {
      unsigned* hw = (pass == 0) ? hist0 : (histP + (pass - 1) * 2 * HPAD);
      const int l4 = lane << 2;
      hw[l4] = 0u; hw[l4 + 1] = 0u; hw[l4 + 2] = 0u; hw[l4 + 3] = 0u;
      const int shift = 24 - 8 * pass;
      #pragma unroll
      for (int q = 0; q < 4; ++q) {
        bool cand = (pass == 0) || ((kq[q] >> (shift + 8)) == prefix);
        if (cand) atomicAdd(&hw[(kq[q] >> shift) & 255u], 1u);
      }
      scan_step(hw, 1, lane, krem, prefix);
    }
    const unsigned T = prefix;
    int total = 0, ttot = 0;
    #pragma unroll
    for (int q = 0; q < 4; ++q) {
      int e = 4 * lane + q;
      bool sel = kq[q] > T;
      unsigned long long m = __ballot(sel);
      if (sel) {
        int slot = total + (int)__popcll(m & lower_mask(lane));
        path_colb[0][slot] = e; path_tb[0][slot] = xv[q];
      }
      total += (int)__popcll(m);
      bool tie = (kq[q] == T);
      unsigned long long tm = __ballot(tie);
      if (tie) {
        int ts = ttot + (int)__popcll(tm & lower_mask(lane));
        if (ts < 128) tieq[ts] = (unsigned)e;
      }
      ttot += (int)__popcll(tm);
    }
    if (lane == 0) {
      int m = ttot > 128 ? 128 : ttot;
      for (int a2 = 1; a2 < m; ++a2) {
        unsigned v = tieq[a2]; int c = a2 - 1;
        while (c >= 0 && tieq[c] > v) { tieq[c + 1] = tieq[c]; --c; }
        tieq[c + 1] = v;
      }
    }
    const int kt = KSEL - total;
    if (lane < kt) {
      int e = (int)tieq[lane];
      path_colb[0][total + lane] = e; path_tb[0][total + lane] = x[b * 256 + e];
    }
  }
  __syncthreads();   // layer-0 paths + A/B + bz visible

  // ================= layers 1,2 =================
  for (int l = 1; l < 3; ++l) {
    const float* w1 = (l == 1) ? s1w1 : s2w1;
    const float* b1 = (l == 1) ? s1b1 : s2b1;
    const float* w2 = (l == 1) ? s1w2 : s2w2;
    const float  b2v = (l == 1) ? s1b2[0] : s2b2[0];
    const float* Wl = (l == 1) ? W1 : W2;
    const float* Wprev = (l == 1) ? W0 : W1;
    const float* WTprev = (l == 1) ? W0T : W1T;
    const int Fout = (l == 2) ? 128 : 256;
    const bool bz = (bz_sh[l] != 0);
    const float* ctp = useWs ? (Ctg + l * 8192) : nullptr;
    const int* path_col = path_colb[l - 1];
    const float* path_t = path_tb[l - 1];
    int* npath_col = path_colb[l & 1];         // l==1 -> buf1; l==2 unused
    float* npath_t = path_tb[l & 1];

    // ---- score phase: 25 elems/thread, e = j*NT + t ; keys -> LDS; inline RLE pass-0 ----
    const int i = t & 255;
    const int pq = t >> 8;
    const float Ai = As[l - 1][i], Bi = Bs[l - 1][i];
    unsigned* histw0 = hist0 + (w >> 1) * HPAD;            // wave-pair copy
    {
      const int l4 = lane << 2;
      histw0[l4] = 0u; histw0[l4 + 1] = 0u; histw0[l4 + 2] = 0u; histw0[l4 + 3] = 0u;
    }
    for (int id = t; id < 2 * HPAD; id += NT) histP[id] = 0u;  // pass-1 hist only
    if (t == 0) { nsel_s = 0; ntie_s = 0; ncand_s = 0; }
    unsigned runD = 0x100u; unsigned runC = 0u;
    if (useWs && bz) {                     // hot path: 8-wide load groups, branch-free inner
      #pragma unroll
      for (int g = 0; g < 25; g += 8) {
        float wv[8], tv[8];
        #pragma unroll
        for (int jj = 0; jj < 8; ++jj) {
          if (g + jj < 25) {
            int p = pq + ((g + jj) << 2);
            tv[jj] = path_t[p];
            wv[jj] = WTprev[(path_col[p] << 8) + i];
          }
        }
        #pragma unroll
        for (int jj = 0; jj < 8; ++jj) {
          if (g + jj < 25) {
            float s = fast_tanhf(wv[jj] * tv[jj]);
            float v = s * (s > 0.f ? Ai : Bi) + b2v;
            unsigned k = fkey(v);
            keyLds[(g + jj) * NT + t] = k;
            unsigned d = k >> 24;
            if (d == runD) ++runC;
            else { if (runC) atomicAdd(&histw0[runD], runC); runD = d; runC = 1u; }
          }
        }
      }
    } else {                               // general path
      #pragma unroll
      for (int g = 0; g < 25; g += 4) {
        float wv[4];
        #pragma unroll
        for (int jj = 0; jj < 4; ++jj) {
          if (g + jj < 25) {
            int p = pq + ((g + jj) << 2);
            wv[jj] = useWs ? WTprev[(path_col[p] << 8) + i]
                           : Wprev[i * 256 + path_col[p]];
          }
        }
        #pragma unroll
        for (int jj = 0; jj < 4; ++jj) {
          if (g + jj < 25) {
            int p = pq + ((g + jj) << 2);
            float s = fast_tanhf(wv[jj] * path_t[p]);
            float v;
            if (bz) v = s * (s > 0.f ? Ai : Bi) + b2v;
            else {
              v = b2v;
              for (int h = 0; h < 32; ++h) {
                float c = useWs ? ctp[h * 256 + i] : slow_c(w1, Wl, Fout, h, i);
                v += w2[h] * fmaxf(fmaf(s, c, b1[h]), 0.f);
              }
            }
            unsigned k = fkey(v);
            keyLds[(g + jj) * NT + t] = k;
            unsigned d = k >> 24;
            if (d == runD) ++runC;
            else { if (runC) atomicAdd(&histw0[runD], runC); runD = d; runC = 1u; }
          }
        }
      }
    }
    if (runC) atomicAdd(&histw0[runD], runC);

    // ---- pass 0 scan ----
    __syncthreads();                                   // b1
    int krem = KSEL; unsigned prefix = 0u;
    scan_step(hist0, NW0, lane, krem, prefix);         // prefix8 (all waves redundantly)

    // ---- pass 1: full read, byte-1 histogram over prefix8 candidates ----
    {
      unsigned* hn = histP + (w & 1) * HPAD;
      #pragma unroll
      for (int j = 0; j < 25; ++j) {
        unsigned k = keyLds[j * NT + t];
        if ((k >> 24) == prefix) atomicAdd(&hn[(k >> 16) & 255u], 1u);
      }
    }
    __syncthreads();                                   // b2
    scan_step(histP, 2, lane, krem, prefix);           // prefix16, krem = slots in tie bin

    // ---- pass 2: full read; early selection (p16>prefix); compact the tie bin ----
    #pragma unroll
    for (int j = 0; j < 25; ++j) {
      unsigned k = keyLds[j * NT + t];
      unsigned p16 = k >> 16;
      if (p16 > prefix) {                              // provably in top-100
        int slot = atomicAdd(&nsel_s, 1);
        int e = j * NT + t; int p = e >> 8;
        float wq = useWs ? WTprev[(path_col[p] << 8) + i] : Wprev[i * 256 + path_col[p]];
        float s = fast_tanhf(wq * path_t[p]);
        sel_col[slot] = i; sel_s[slot] = s; sel_sc[slot] = unfkey(k);
        if (l == 1) { npath_col[slot] = i; npath_t[slot] = s; }
      } else if (p16 == prefix) {
        int ci = atomicAdd(&ncand_s, 1);
        if (ci < CCAP) { candK[ci] = k; candE[ci] = j * NT + t; }
      }
    }
    __syncthreads();                                   // b3: candidates complete
    const int ncand = ncand_s;

    if (ncand <= CCAP) {
      // ---- rank-select over compact list: exact stable top-krem (value desc, idx asc) ----
      for (int idx = t; idx < ncand; idx += NT) {
        unsigned k = candK[idx]; int e = candE[idx];
        int rnk = 0;
        for (int j2 = 0; j2 < ncand; ++j2) {
          unsigned kj = candK[j2];
          rnk += (kj > k) || (kj == k && candE[j2] < e);
        }
        if (rnk < krem) {
          int slot = atomicAdd(&nsel_s, 1);
          int ii = e & 255, p = e >> 8;
          float wq = useWs ? WTprev[(path_col[p] << 8) + ii] : Wprev[ii * 256 + path_col[p]];
          float s = fast_tanhf(wq * path_t[p]);
          sel_col[slot] = ii; sel_s[slot] = s; sel_sc[slot] = unfkey(k);
          if (l == 1) { npath_col[slot] = ii; npath_t[slot] = s; }
        }
      }
      __syncthreads();                                 // b4: selection (and paths) final
    } else {
      // ---- rare fallback: classic passes 2,3 over full keyLds ----
      for (int id = 2 * HPAD + t; id < 6 * HPAD; id += NT) histP[id] = 0u;
      __syncthreads();
      {
        unsigned* hn = histP + 2 * HPAD + (w & 1) * HPAD;
        #pragma unroll
        for (int j = 0; j < 25; ++j) {
          unsigned k = keyLds[j * NT + t];
          if ((k >> 16) == prefix) atomicAdd(&hn[(k >> 8) & 255u], 1u);
        }
      }
      __syncthreads();
      scan_step(histP + 2 * HPAD, 2, lane, krem, prefix); // prefix24
      {
        unsigned* hn = histP + 4 * HPAD + (w & 1) * HPAD;
        #pragma unroll
        for (int j = 0; j < 25; ++j) {
          unsigned k = keyLds[j * NT + t];
          if ((k >> 8) == prefix) atomicAdd(&hn[k & 255u], 1u);
        }
      }
      __syncthreads();
      scan_step(histP + 4 * HPAD, 2, lane, krem, prefix); // T
      const unsigned T = prefix;
      #pragma unroll
      for (int j = 0; j < 25; ++j) {
        unsigned k = keyLds[j * NT + t];
        if ((k >> 16) == (T >> 16)) {
          int e = j * NT + t;
          if (k > T) {
            int slot = atomicAdd(&nsel_s, 1);
            int p = e >> 8;
            float wq = useWs ? WTprev[(path_col[p] << 8) + i] : Wprev[i * 256 + path_col[p]];
            float s = fast_tanhf(wq * path_t[p]);
            sel_col[slot] = i; sel_s[slot] = s; sel_sc[slot] = unfkey(k);
            if (l == 1) { npath_col[slot] = i; npath_t[slot] = s; }
          } else if (k == T) {
            int tp = atomicAdd(&ntie_s, 1);
            if (tp < 128) tieq[tp] = (unsigned)e;
          }
        }
      }
      __syncthreads();                                 // selection complete (ex ties)
      if (w == 0) {                                    // wave 0: ties ascending by elem id
        const int G = nsel_s;
        const int kt = KSEL - G;
        if (lane == 0 && kt > 1) {
          int m = ntie_s > 128 ? 128 : ntie_s;
          for (int a2 = 1; a2 < m; ++a2) {
            unsigned v = tieq[a2]; int c = a2 - 1;
            while (c >= 0 && tieq[c] > v) { tieq[c + 1] = tieq[c]; --c; }
            tieq[c + 1] = v;
          }
        }
        if (lane < kt) {
          int e = (int)tieq[lane];
          int ii = e & 255, p = e >> 8;
          float wq = useWs ? WTprev[(path_col[p] << 8) + ii] : Wprev[ii * 256 + path_col[p]];
          float s = fast_tanhf(wq * path_t[p]);
          sel_col[G + lane] = ii; sel_s[G + lane] = s; sel_sc[G + lane] = unfkey(T);
          if (l == 1) { npath_col[G + lane] = ii; npath_t[G + lane] = s; }
        }
      }
      __syncthreads();                                 // paths / sel final
    }
  }

  // ================= epilogue =================
  if (w == 0) {
    float s1v = sel_sc[lane];
    float s2v = (lane < 36) ? sel_sc[64 + lane] : -INFINITY;
    float m = fmaxf(s1v, s2v);
    #pragma unroll
    for (int off = 32; off >= 1; off >>= 1) m = fmaxf(m, __shfl_xor(m, off, 64));
    float e1 = expf(s1v - m);
    float e2 = (lane < 36) ? expf(s2v - m) : 0.f;
    float sv = e1 + e2;
    #pragma unroll
    for (int off = 32; off >= 1; off >>= 1) sv += __shfl_xor(sv, off, 64);
    wts[lane] = e1 * sel_s[lane] / sv;
    if (lane < 36) wts[64 + lane] = e2 * sel_s[64 + lane] / sv;
  }
  __syncthreads();
  {
    const int chunk = w >> 1, half = w & 1;
    const int o = half * 64 + lane;
    const int pb = chunk * 13;
    const int pe = (pb + 13 < KSEL) ? pb + 13 : KSEL;
    float acc = 0.f;
    for (int p = pb; p < pe; ++p) {
      float wq = useWs ? W2T[sel_col[p] * 128 + o] : W2[o * 256 + sel_col[p]];
      acc = fmaf(wq, wts[p], acc);
    }
    partial[chunk][o] = acc;
  }
  __syncthreads();
  if (t < 128) {
    float acc = 0.f;
    #pragma unroll
    for (int c = 0; c < 8; ++c) acc += partial[c][t];
    out[b * 128 + t] = acc;
  }
}

extern "C" void kernel_launch(void* const* d_in, const int* in_sizes, int n_in,
                              void* d_out, int out_size, void* d_ws, size_t ws_size,
                              hipStream_t stream) {
  const float* x    = (const float*)d_in[0];
  const float* W0   = (const float*)d_in[1];
  const float* s0w1 = (const float*)d_in[2];
  const float* s0b1 = (const float*)d_in[3];
  const float* s0w2 = (const float*)d_in[4];
  const float* s0b2 = (const float*)d_in[5];
  const float* W1   = (const float*)d_in[6];
  const float* s1w1 = (const float*)d_in[7];
  const float* s1b1 = (const float*)d_in[8];
  const float* s1w2 = (const float*)d_in[9];
  const float* s1b2 = (const float*)d_in[10];
  const float* W2   = (const float*)d_in[11];
  const float* s2w1 = (const float*)d_in[12];
  const float* s2b1 = (const float*)d_in[13];
  const float* s2w2 = (const float*)d_in[14];
  const float* s2b2 = (const float*)d_in[15];
  float* out = (float*)d_out;
  float* ws  = (float*)d_ws;

  const bool haveWs = ws_size >= (size_t)WS_FLOATS * sizeof(float);
  const float* wsr = nullptr;
  if (haveWs) {
    pqn_precompute<<<136, 256, 0, stream>>>(W0, W1, W2, s0w1, s1w1, s2w1, ws);
    wsr = ws;
  }
  pqn_main<<<16, NT, 0, stream>>>(x, W0, W1, W2,
                                  s0w1, s1w1, s2w1,
                                  s0b1, s1b1, s2b1,
                                  s0w2, s1w2, s2w2,
                                  s0b2, s1b2, s2b2,
                                  wsr, out);
}